// Round 16
// baseline (60.220 us; speedup 1.0000x reference)
//
#include <hip/hip_runtime.h>
#include <hip/hip_bf16.h>
#include <math.h>

#define N_TOK 4096
#define M_TOK 1024
#define DMODEL 512
#define NHEAD 8
#define DHEAD 64
#define LOG2E 1.44269504f

typedef __attribute__((ext_vector_type(8))) short short8;
typedef __attribute__((ext_vector_type(4))) float f32x4;
typedef __attribute__((ext_vector_type(4))) float float4v;

static __device__ __forceinline__ short f2bf(float f) {
    union { float f; unsigned u; } v; v.f = f;
    unsigned r = v.u + 0x7fffu + ((v.u >> 16) & 1u);
    return (short)(r >> 16);
}

// ---------------------------------------------------------------------------
// Pack v2 (r11-proven). Blocks [0,192): wq/wk/wv head-tile transposes via
// LDS. Blocks [192,256): wo. Blocks [256+): xv/xt bf16 conversion.
// ---------------------------------------------------------------------------
__global__ __launch_bounds__(256) void pack_kernel(
        const float* __restrict__ xv, const float* __restrict__ xt,
        const float* __restrict__ wq, const float* __restrict__ wk,
        const float* __restrict__ wv, const float* __restrict__ wo,
        short* __restrict__ xvb, short* __restrict__ xtb,
        short* __restrict__ wqb, short* __restrict__ wkb,
        short* __restrict__ wvb, short* __restrict__ wob) {
    int bid = blockIdx.x;
    int t = threadIdx.x;
    if (bid < 256) {
        __shared__ float lds[64][65];
        const float* src;
        short* dst;
        int srstride;
        int dr0, dc0;
        if (bid < 192) {
            int mat = bid >> 6;
            int hb = bid & 63;
            int h = hb >> 3, dt = hb & 7;
            const float* W = (mat == 0) ? wq : (mat == 1) ? wk : wv;
            src = W + (size_t)h * (DMODEL * DHEAD) + (size_t)(dt * 64) * DHEAD;
            srstride = DHEAD;
            dst = (mat == 0) ? wqb : (mat == 1) ? wkb : wvb;
            dr0 = h * 64;
            dc0 = dt * 64;
        } else {
            int b = bid - 192;
            int rt = b >> 3, ct = b & 7;
            src = wo + (size_t)(rt * 64) * DMODEL + ct * 64;
            srstride = DMODEL;
            dst = wob;
            dr0 = ct * 64;
            dc0 = rt * 64;
        }
        {
            int r = t >> 2, c0 = (t & 3) * 16;
            const float* s = src + (size_t)r * srstride + c0;
            #pragma unroll
            for (int j = 0; j < 4; j++) {
                float4v v = *(const float4v*)(s + j * 4);
                lds[r][c0 + j * 4 + 0] = v[0];
                lds[r][c0 + j * 4 + 1] = v[1];
                lds[r][c0 + j * 4 + 2] = v[2];
                lds[r][c0 + j * 4 + 3] = v[3];
            }
        }
        __syncthreads();
        {
            int outr = t >> 2, c0 = (t & 3) * 16;
            short8 o0, o1;
            #pragma unroll
            for (int j = 0; j < 8; j++) {
                o0[j] = f2bf(lds[c0 + j][outr]);
                o1[j] = f2bf(lds[c0 + 8 + j][outr]);
            }
            short* d = dst + (size_t)(dr0 + outr) * DMODEL + dc0 + c0;
            *(short8*)d = o0;
            *(short8*)(d + 8) = o1;
        }
        return;
    }
    int idx = (bid - 256) * 256 + t;
    int stride = (gridDim.x - 256) * 256;
    const int CXV = N_TOK * DMODEL / 8;
    const int CXT = M_TOK * DMODEL / 8;
    for (int c = idx; c < CXV; c += stride) {
        float4v f0 = *(const float4v*)&xv[c * 8];
        float4v f1 = *(const float4v*)&xv[c * 8 + 4];
        short8 o;
        #pragma unroll
        for (int j = 0; j < 4; j++) { o[j] = f2bf(f0[j]); o[j + 4] = f2bf(f1[j]); }
        *(short8*)&xvb[c * 8] = o;
    }
    for (int c = idx; c < CXT; c += stride) {
        float4v f0 = *(const float4v*)&xt[c * 8];
        float4v f1 = *(const float4v*)&xt[c * 8 + 4];
        short8 o;
        #pragma unroll
        for (int j = 0; j < 4; j++) { o[j] = f2bf(f0[j]); o[j + 4] = f2bf(f1[j]); }
        *(short8*)&xtb[c * 8] = o;
    }
}

// ---------------------------------------------------------------------------
// GEMM body v4 (r14-proven): 64x64 tile, BK=64, 8 waves (512 threads), wave
// w owns 16x32 (1x2 frags). Reg-staging + prefetch-after-barrier.
// ---------------------------------------------------------------------------
template<typename EPI>
static __device__ __forceinline__ void gemm_body8(const short* __restrict__ A,
                                                  const short* __restrict__ BT,
                                                  int m0, int n0, EPI epi) {
    __shared__ __align__(16) short As[64][72];
    __shared__ __align__(16) short Bs[64][72];
    int t = threadIdx.x;
    int lane = t & 63, w = t >> 6;
    int wr = w & 3, wc = w >> 2;
    int l15 = lane & 15, g = lane >> 4;

    int row = t >> 3, c0 = (t & 7) * 8;
    const short* gA = A + (size_t)(m0 + row) * DMODEL + c0;
    const short* gB = BT + (size_t)(n0 + row) * DMODEL + c0;

    short8 ra = *(const short8*)gA;
    short8 rb = *(const short8*)gB;

    f32x4 acc[2] = {};
    #pragma unroll
    for (int step = 0; step < DMODEL / 64; ++step) {
        *(short8*)&As[row][c0] = ra;
        *(short8*)&Bs[row][c0] = rb;
        __syncthreads();
        if (step < DMODEL / 64 - 1) {
            gA += 64; gB += 64;
            ra = *(const short8*)gA;
            rb = *(const short8*)gB;
        }
        #pragma unroll
        for (int ks = 0; ks < 2; ks++) {
            short8 a = *(short8*)&As[wr * 16 + l15][ks * 32 + g * 8];
            #pragma unroll
            for (int fc = 0; fc < 2; fc++) {
                short8 b = *(short8*)&Bs[wc * 32 + fc * 16 + l15][ks * 32 + g * 8];
                acc[fc] = __builtin_amdgcn_mfma_f32_16x16x32_bf16(a, b, acc[fc], 0, 0, 0);
            }
        }
        __syncthreads();
    }
    #pragma unroll
    for (int fc = 0; fc < 2; fc++)
        #pragma unroll
        for (int r = 0; r < 4; r++) {
            int orow = m0 + wr * 16 + g * 4 + r;
            int ocol = n0 + wc * 32 + fc * 16 + l15;
            epi(orow, ocol, acc[fc][r]);
        }
}

// ---------------------------------------------------------------------------
// K, V projections. 256 blocks x 512 threads. K pre-scaled by LOG2E.
// ---------------------------------------------------------------------------
__global__ __launch_bounds__(512) void gemmKV(const short* __restrict__ xtb,
                                              const short* __restrict__ wkb,
                                              const short* __restrict__ wvb,
                                              short* __restrict__ kbm,
                                              short* __restrict__ vbt) {
    int bx = blockIdx.x;
    if (bx < 128) {
        gemm_body8(xtb, wkb, (bx >> 3) * 64, (bx & 7) * 64,
                   [&](int row, int col, float v) { kbm[(size_t)row * DMODEL + col] = f2bf(v * LOG2E); });
    } else {
        int b = bx - 128;
        gemm_body8(xtb, wvb, (b >> 3) * 64, (b & 7) * 64,
                   [&](int row, int col, float v) { vbt[(size_t)col * M_TOK + row] = f2bf(v); });
    }
}

// ---------------------------------------------------------------------------
// Final GEMM: out = Y * Wout(^T stored) + PE. (64,8) x 512 threads.
// ---------------------------------------------------------------------------
__global__ __launch_bounds__(512) void gemmOut(const short* __restrict__ A,
                                               const short* __restrict__ BT,
                                               float* __restrict__ Cout) {
    __shared__ float ifreq[256];
    if (threadIdx.x < 256)
        ifreq[threadIdx.x] = __expf(-(float)threadIdx.x * (9.210340371976184f / 512.0f));
    __syncthreads();
    gemm_body8(A, BT, blockIdx.x * 64, blockIdx.y * 64,
               [&](int row, int col, float v) {
                   float x = (float)row * ifreq[col >> 1];
                   float s, c;
                   __sincosf(x, &s, &c);
                   Cout[(size_t)row * DMODEL + col] = v + ((col & 1) ? c : s);
               });
}

// ---------------------------------------------------------------------------
// Attention v9: fused Q-projection + 2q x 2kh x 2keysub wave remap.
// Each wave: 32 q-rows x 32-key subtile per iter -> K/V fragment reads are
// shared across 2 q-frags: 10 ds_read_b128 per 16 MFMA (was 18). Single-pass
// exp2 softmax (LOG2E in K), 4-way plain-sum merge via LDS overlay.
// ---------------------------------------------------------------------------
struct AttnS {
    short Ks[2][64][72];    // [kh][key][d]
    short Vt[2][64][72];    // [kh][d][key]
    short Ps[8][32][40];    // per-wave P: 32 q x 32 keys
};
struct MergeS {
    f32x4 macc[2][3][2][4][64];  // [qg][grp-1][s][nt][lane]
    f32x4 mrs[2][3][2][64];      // [qg][grp-1][s][lane]
};
struct GemmS {
    short As[64][72];
    short Bs[64][72];
};
union AttnU { AttnS a; MergeS m; GemmS g; };

__global__ __launch_bounds__(512) void attn_kernel(const short* __restrict__ xvb,
                                                   const short* __restrict__ wqb,
                                                   const short* __restrict__ Kb,
                                                   const short* __restrict__ VbT,
                                                   short* __restrict__ Yb) {
    __shared__ __align__(16) AttnU u;
    __shared__ __align__(16) short Qs[64][72];

    int bid = blockIdx.x;
    int h = bid & 7;
    int n0 = (bid >> 3) * 64;
    int t = threadIdx.x;
    int lane = t & 63, w = t >> 6;
    int qg = w >> 2, kh = (w >> 1) & 1, half = w & 1;
    int l15 = lane & 15, g = lane >> 4;

    // ---- Q-projection prologue (gemm_body8 pattern into Qs) ----
    {
        int row = t >> 3, c0 = (t & 7) * 8;
        const short* gA = xvb + (size_t)(n0 + row) * DMODEL + c0;
        const short* gB = wqb + (size_t)(h * DHEAD + row) * DMODEL + c0;
        short8 ra = *(const short8*)gA;
        short8 rb = *(const short8*)gB;
        int wr = w & 3, wc = w >> 2;
        f32x4 qacc[2] = {};
        #pragma unroll
        for (int step = 0; step < DMODEL / 64; ++step) {
            *(short8*)&u.g.As[row][c0] = ra;
            *(short8*)&u.g.Bs[row][c0] = rb;
            __syncthreads();
            if (step < DMODEL / 64 - 1) {
                gA += 64; gB += 64;
                ra = *(const short8*)gA;
                rb = *(const short8*)gB;
            }
            #pragma unroll
            for (int ks = 0; ks < 2; ks++) {
                short8 a = *(short8*)&u.g.As[wr * 16 + l15][ks * 32 + g * 8];
                #pragma unroll
                for (int fc = 0; fc < 2; fc++) {
                    short8 b = *(short8*)&u.g.Bs[wc * 32 + fc * 16 + l15][ks * 32 + g * 8];
                    qacc[fc] = __builtin_amdgcn_mfma_f32_16x16x32_bf16(a, b, qacc[fc], 0, 0, 0);
                }
            }
            __syncthreads();
        }
        #pragma unroll
        for (int fc = 0; fc < 2; fc++)
            #pragma unroll
            for (int r = 0; r < 4; r++)
                Qs[wr * 16 + g * 4 + r][wc * 32 + fc * 16 + l15] = f2bf(qacc[fc][r]);
        __syncthreads();
    }

    // hoist Q fragments: 32 q-rows (2 sub-frags) x 2 d-halves
    short8 qa[2][2];
    #pragma unroll
    for (int s = 0; s < 2; s++)
        #pragma unroll
        for (int d = 0; d < 2; d++)
            qa[s][d] = *(short8*)&Qs[qg * 32 + s * 16 + l15][d * 32 + g * 8];

    // ---- K/V staging pointers (threads [0,256) stage kh=0, rest kh=1) ----
    int sh = t >> 8;
    int tt = t & 255;
    int row = tt >> 2, c0 = (tt & 3) * 16;
    const short* gK = Kb + (size_t)(sh * 512 + row) * DMODEL + h * DHEAD + c0;
    const short* gV = VbT + (size_t)(h * DHEAD + row) * M_TOK + sh * 512 + c0;

    short8 k0 = *(const short8*)gK;
    short8 k1 = *(const short8*)(gK + 8);
    short8 v0 = *(const short8*)gV;
    short8 v1 = *(const short8*)(gV + 8);

    f32x4 acc[2][4] = {};
    f32x4 rsum[2] = {};

    for (int it = 0; it < 8; ++it) {
        *(short8*)&u.a.Ks[sh][row][c0]     = k0;
        *(short8*)&u.a.Ks[sh][row][c0 + 8] = k1;
        *(short8*)&u.a.Vt[sh][row][c0]     = v0;
        *(short8*)&u.a.Vt[sh][row][c0 + 8] = v1;
        __syncthreads();
        if (it < 7) {
            gK += (size_t)64 * DMODEL;
            gV += 64;
            k0 = *(const short8*)gK;
            k1 = *(const short8*)(gK + 8);
            v0 = *(const short8*)gV;
            v1 = *(const short8*)(gV + 8);
        }
        // QK^T: this wave's 32-key subtile (half), 2 x 16-key tiles, 2 q-frags
        #pragma unroll
        for (int ktl = 0; ktl < 2; ktl++) {
            int kt = half * 2 + ktl;
            short8 kf0 = *(short8*)&u.a.Ks[kh][kt * 16 + l15][g * 8];
            short8 kf1 = *(short8*)&u.a.Ks[kh][kt * 16 + l15][32 + g * 8];
            #pragma unroll
            for (int s = 0; s < 2; s++) {
                f32x4 e = {};
                e = __builtin_amdgcn_mfma_f32_16x16x32_bf16(qa[s][0], kf0, e, 0, 0, 0);
                e = __builtin_amdgcn_mfma_f32_16x16x32_bf16(qa[s][1], kf1, e, 0, 0, 0);
                #pragma unroll
                for (int r = 0; r < 4; r++) {
                    float p = exp2f(e[r]);       // LOG2E folded into K
                    rsum[s][r] += p;
                    u.a.Ps[w][s * 16 + g * 4 + r][ktl * 16 + l15] = f2bf(p);
                }
            }
        }
        // PV: this wave's 32 keys, 2 q-frags share each V fragment
        short8 pa[2];
        #pragma unroll
        for (int s = 0; s < 2; s++) pa[s] = *(short8*)&u.a.Ps[w][s * 16 + l15][g * 8];
        #pragma unroll
        for (int nt = 0; nt < 4; nt++) {
            short8 vf = *(short8*)&u.a.Vt[kh][nt * 16 + l15][half * 32 + g * 8];
            #pragma unroll
            for (int s = 0; s < 2; s++)
                acc[s][nt] = __builtin_amdgcn_mfma_f32_16x16x32_bf16(pa[s], vf, acc[s][nt], 0, 0, 0);
        }
        __syncthreads();
    }

    // 4-way merge within each qg (plain sum; overlay aliases staging LDS)
    int grp = w & 3;
    if (grp != 0) {
        #pragma unroll
        for (int s = 0; s < 2; s++) {
            #pragma unroll
            for (int nt = 0; nt < 4; nt++) u.m.macc[qg][grp - 1][s][nt][lane] = acc[s][nt];
            u.m.mrs[qg][grp - 1][s][lane] = rsum[s];
        }
    }
    __syncthreads();
    if (grp == 0) {
        #pragma unroll
        for (int gi = 0; gi < 3; gi++)
            #pragma unroll
            for (int s = 0; s < 2; s++) {
                #pragma unroll
                for (int nt = 0; nt < 4; nt++) acc[s][nt] += u.m.macc[qg][gi][s][nt][lane];
                rsum[s] += u.m.mrs[qg][gi][s][lane];
            }
        #pragma unroll
        for (int s = 0; s < 2; s++)
            #pragma unroll
            for (int r = 0; r < 4; r++) {
                float v = rsum[s][r];
                v += __shfl_xor(v, 1);
                v += __shfl_xor(v, 2);
                v += __shfl_xor(v, 4);
                v += __shfl_xor(v, 8);
                rsum[s][r] = v;
            }
        #pragma unroll
        for (int s = 0; s < 2; s++)
            #pragma unroll
            for (int nt = 0; nt < 4; nt++)
                #pragma unroll
                for (int r = 0; r < 4; r++) {
                    float y = acc[s][nt][r] / rsum[s][r];
                    Yb[(size_t)(n0 + qg * 32 + s * 16 + g * 4 + r) * DMODEL + h * DHEAD + nt * 16 + l15] = f2bf(y);
                }
    }
}

// ---------------------------------------------------------------------------
extern "C" void kernel_launch(void* const* d_in, const int* in_sizes, int n_in,
                              void* d_out, int out_size, void* d_ws, size_t ws_size,
                              hipStream_t stream) {
    const float* xv = (const float*)d_in[0];
    const float* xt = (const float*)d_in[1];
    const float* wq = (const float*)d_in[2];
    const float* wk = (const float*)d_in[3];
    const float* wv = (const float*)d_in[4];
    const float* wo = (const float*)d_in[5];

    short* xvb = (short*)d_ws;              // 4096*512
    short* xtb = xvb + N_TOK * DMODEL;      // 1024*512
    short* wqb = xtb + M_TOK * DMODEL;      // 512*512 (B^T)
    short* wkb = wqb + DMODEL * DMODEL;
    short* wvb = wkb + DMODEL * DMODEL;
    short* wob = wvb + DMODEL * DMODEL;
    short* kbm = wob + DMODEL * DMODEL;     // 1024*512 (pre-scaled by LOG2E)
    short* vbt = kbm + M_TOK * DMODEL;      // 512*1024 (V^T)
    short* yb  = vbt + M_TOK * DMODEL;      // 4096*512

    pack_kernel<<<1280, 256, 0, stream>>>(xv, xt, wq, wk, wv, wo,
                                          xvb, xtb, wqb, wkb, wvb, wob);
    gemmKV<<<256, 512, 0, stream>>>(xtb, wkb, wvb, kbm, vbt);
    attn_kernel<<<512, 512, 0, stream>>>(xvb, wqb, kbm, vbt, yb);
    gemmOut<<<dim3(64, 8), 512, 0, stream>>>(yb, wob, (float*)d_out);
}

// Round 18
// 51.312 us; speedup vs baseline: 1.1736x; 1.1736x over previous
//
#include <hip/hip_runtime.h>
#include <hip/hip_bf16.h>
#include <math.h>

#define N_TOK 4096
#define M_TOK 1024
#define DMODEL 512
#define NHEAD 8
#define DHEAD 64
#define LOG2E 1.44269504f

typedef __attribute__((ext_vector_type(8))) short short8;
typedef __attribute__((ext_vector_type(4))) float f32x4;
typedef __attribute__((ext_vector_type(4))) float float4v;

static __device__ __forceinline__ short f2bf(float f) {
    union { float f; unsigned u; } v; v.f = f;
    unsigned r = v.u + 0x7fffu + ((v.u >> 16) & 1u);
    return (short)(r >> 16);
}

// ---------------------------------------------------------------------------
// Pack v2 (r11-proven). Blocks [0,192): wq/wk/wv head-tile transposes via
// LDS. Blocks [192,256): wo. Blocks [256+): xv/xt bf16 conversion.
// ---------------------------------------------------------------------------
__global__ __launch_bounds__(256) void pack_kernel(
        const float* __restrict__ xv, const float* __restrict__ xt,
        const float* __restrict__ wq, const float* __restrict__ wk,
        const float* __restrict__ wv, const float* __restrict__ wo,
        short* __restrict__ xvb, short* __restrict__ xtb,
        short* __restrict__ wqb, short* __restrict__ wkb,
        short* __restrict__ wvb, short* __restrict__ wob) {
    int bid = blockIdx.x;
    int t = threadIdx.x;
    if (bid < 256) {
        __shared__ float lds[64][65];
        const float* src;
        short* dst;
        int srstride;
        int dr0, dc0;
        if (bid < 192) {
            int mat = bid >> 6;
            int hb = bid & 63;
            int h = hb >> 3, dt = hb & 7;
            const float* W = (mat == 0) ? wq : (mat == 1) ? wk : wv;
            src = W + (size_t)h * (DMODEL * DHEAD) + (size_t)(dt * 64) * DHEAD;
            srstride = DHEAD;
            dst = (mat == 0) ? wqb : (mat == 1) ? wkb : wvb;
            dr0 = h * 64;
            dc0 = dt * 64;
        } else {
            int b = bid - 192;
            int rt = b >> 3, ct = b & 7;
            src = wo + (size_t)(rt * 64) * DMODEL + ct * 64;
            srstride = DMODEL;
            dst = wob;
            dr0 = ct * 64;
            dc0 = rt * 64;
        }
        {
            int r = t >> 2, c0 = (t & 3) * 16;
            const float* s = src + (size_t)r * srstride + c0;
            #pragma unroll
            for (int j = 0; j < 4; j++) {
                float4v v = *(const float4v*)(s + j * 4);
                lds[r][c0 + j * 4 + 0] = v[0];
                lds[r][c0 + j * 4 + 1] = v[1];
                lds[r][c0 + j * 4 + 2] = v[2];
                lds[r][c0 + j * 4 + 3] = v[3];
            }
        }
        __syncthreads();
        {
            int outr = t >> 2, c0 = (t & 3) * 16;
            short8 o0, o1;
            #pragma unroll
            for (int j = 0; j < 8; j++) {
                o0[j] = f2bf(lds[c0 + j][outr]);
                o1[j] = f2bf(lds[c0 + 8 + j][outr]);
            }
            short* d = dst + (size_t)(dr0 + outr) * DMODEL + dc0 + c0;
            *(short8*)d = o0;
            *(short8*)(d + 8) = o1;
        }
        return;
    }
    int idx = (bid - 256) * 256 + t;
    int stride = (gridDim.x - 256) * 256;
    const int CXV = N_TOK * DMODEL / 8;
    const int CXT = M_TOK * DMODEL / 8;
    for (int c = idx; c < CXV; c += stride) {
        float4v f0 = *(const float4v*)&xv[c * 8];
        float4v f1 = *(const float4v*)&xv[c * 8 + 4];
        short8 o;
        #pragma unroll
        for (int j = 0; j < 4; j++) { o[j] = f2bf(f0[j]); o[j + 4] = f2bf(f1[j]); }
        *(short8*)&xvb[c * 8] = o;
    }
    for (int c = idx; c < CXT; c += stride) {
        float4v f0 = *(const float4v*)&xt[c * 8];
        float4v f1 = *(const float4v*)&xt[c * 8 + 4];
        short8 o;
        #pragma unroll
        for (int j = 0; j < 4; j++) { o[j] = f2bf(f0[j]); o[j + 4] = f2bf(f1[j]); }
        *(short8*)&xtb[c * 8] = o;
    }
}

// ---------------------------------------------------------------------------
// GEMM body v4 (r14-proven): 64x64 tile, BK=64, 8 waves (512 threads), wave
// w owns 16x32 (1x2 frags). Reg-staging + prefetch-after-barrier.
// ---------------------------------------------------------------------------
template<typename EPI>
static __device__ __forceinline__ void gemm_body8(const short* __restrict__ A,
                                                  const short* __restrict__ BT,
                                                  int m0, int n0, EPI epi) {
    __shared__ __align__(16) short As[64][72];
    __shared__ __align__(16) short Bs[64][72];
    int t = threadIdx.x;
    int lane = t & 63, w = t >> 6;
    int wr = w & 3, wc = w >> 2;
    int l15 = lane & 15, g = lane >> 4;

    int row = t >> 3, c0 = (t & 7) * 8;
    const short* gA = A + (size_t)(m0 + row) * DMODEL + c0;
    const short* gB = BT + (size_t)(n0 + row) * DMODEL + c0;

    short8 ra = *(const short8*)gA;
    short8 rb = *(const short8*)gB;

    f32x4 acc[2] = {};
    #pragma unroll
    for (int step = 0; step < DMODEL / 64; ++step) {
        *(short8*)&As[row][c0] = ra;
        *(short8*)&Bs[row][c0] = rb;
        __syncthreads();
        if (step < DMODEL / 64 - 1) {
            gA += 64; gB += 64;
            ra = *(const short8*)gA;
            rb = *(const short8*)gB;
        }
        #pragma unroll
        for (int ks = 0; ks < 2; ks++) {
            short8 a = *(short8*)&As[wr * 16 + l15][ks * 32 + g * 8];
            #pragma unroll
            for (int fc = 0; fc < 2; fc++) {
                short8 b = *(short8*)&Bs[wc * 32 + fc * 16 + l15][ks * 32 + g * 8];
                acc[fc] = __builtin_amdgcn_mfma_f32_16x16x32_bf16(a, b, acc[fc], 0, 0, 0);
            }
        }
        __syncthreads();
    }
    #pragma unroll
    for (int fc = 0; fc < 2; fc++)
        #pragma unroll
        for (int r = 0; r < 4; r++) {
            int orow = m0 + wr * 16 + g * 4 + r;
            int ocol = n0 + wc * 32 + fc * 16 + l15;
            epi(orow, ocol, acc[fc][r]);
        }
}

// ---------------------------------------------------------------------------
// K, V projections. 256 blocks x 512 threads. K pre-scaled by LOG2E.
// ---------------------------------------------------------------------------
__global__ __launch_bounds__(512) void gemmKV(const short* __restrict__ xtb,
                                              const short* __restrict__ wkb,
                                              const short* __restrict__ wvb,
                                              short* __restrict__ kbm,
                                              short* __restrict__ vbt) {
    int bx = blockIdx.x;
    if (bx < 128) {
        gemm_body8(xtb, wkb, (bx >> 3) * 64, (bx & 7) * 64,
                   [&](int row, int col, float v) { kbm[(size_t)row * DMODEL + col] = f2bf(v * LOG2E); });
    } else {
        int b = bx - 128;
        gemm_body8(xtb, wvb, (b >> 3) * 64, (b & 7) * 64,
                   [&](int row, int col, float v) { vbt[(size_t)col * M_TOK + row] = f2bf(v); });
    }
}

// ---------------------------------------------------------------------------
// Final GEMM: out = Y * Wout(^T stored) + PE. (64,8) x 512 threads.
// ---------------------------------------------------------------------------
__global__ __launch_bounds__(512) void gemmOut(const short* __restrict__ A,
                                               const short* __restrict__ BT,
                                               float* __restrict__ Cout) {
    __shared__ float ifreq[256];
    if (threadIdx.x < 256)
        ifreq[threadIdx.x] = __expf(-(float)threadIdx.x * (9.210340371976184f / 512.0f));
    __syncthreads();
    gemm_body8(A, BT, blockIdx.x * 64, blockIdx.y * 64,
               [&](int row, int col, float v) {
                   float x = (float)row * ifreq[col >> 1];
                   float pe = (col & 1) ? __cosf(x) : __sinf(x);
                   Cout[(size_t)row * DMODEL + col] = v + pe;
               });
}

// ---------------------------------------------------------------------------
// Attention v8b: same schedule as r15 (fused Q prologue, 4 q-subtiles x 2
// key-halves, reg-staged K/V, single-pass exp2 softmax), but LDS DE-ALIASED:
// Ks/Vt/Ps/Qs dedicated; only prologue GemmS and the end-of-kernel merge
// share one region (separated by the whole main loop). Merge is two
// half-passes through a 12 KB buffer. Total LDS 81408 B -> 2 blocks/CU.
// ---------------------------------------------------------------------------
struct GemmS {
    short As[64][72];
    short Bs[64][72];
};
struct Merge2 {
    f32x4 macc[4][2][64];   // [qg][j][lane]
    f32x4 mrs[4][64];       // [qg][lane]
};
union ProMerge { GemmS g; Merge2 m; };

__global__ __launch_bounds__(512) void attn_kernel(const short* __restrict__ xvb,
                                                   const short* __restrict__ wqb,
                                                   const short* __restrict__ Kb,
                                                   const short* __restrict__ VbT,
                                                   short* __restrict__ Yb) {
    __shared__ __align__(16) short Ks[2][64][72];   // 18432 B (dedicated)
    __shared__ __align__(16) short Vt[2][64][72];   // 18432 B (dedicated)
    __shared__ __align__(16) short Ps[8][16][68];   // 17408 B (dedicated)
    __shared__ __align__(16) short Qs[64][68];      //  8704 B (dedicated)
    __shared__ __align__(16) ProMerge pm;           // 18432 B (prologue/merge)

    int bid = blockIdx.x;
    int h = bid & 7;
    int n0 = (bid >> 3) * 64;
    int t = threadIdx.x;
    int lane = t & 63, w = t >> 6;
    int qg = w & 3, kh = w >> 2;
    int l15 = lane & 15, g = lane >> 4;

    // ---- Q-projection prologue (gemm_body8 pattern into Qs) ----
    {
        int row = t >> 3, c0 = (t & 7) * 8;
        const short* gA = xvb + (size_t)(n0 + row) * DMODEL + c0;
        const short* gB = wqb + (size_t)(h * DHEAD + row) * DMODEL + c0;
        short8 ra = *(const short8*)gA;
        short8 rb = *(const short8*)gB;
        int wr = w & 3, wc = w >> 2;
        f32x4 qacc[2] = {};
        #pragma unroll
        for (int step = 0; step < DMODEL / 64; ++step) {
            *(short8*)&pm.g.As[row][c0] = ra;
            *(short8*)&pm.g.Bs[row][c0] = rb;
            __syncthreads();
            if (step < DMODEL / 64 - 1) {
                gA += 64; gB += 64;
                ra = *(const short8*)gA;
                rb = *(const short8*)gB;
            }
            #pragma unroll
            for (int ks = 0; ks < 2; ks++) {
                short8 a = *(short8*)&pm.g.As[wr * 16 + l15][ks * 32 + g * 8];
                #pragma unroll
                for (int fc = 0; fc < 2; fc++) {
                    short8 b = *(short8*)&pm.g.Bs[wc * 32 + fc * 16 + l15][ks * 32 + g * 8];
                    qacc[fc] = __builtin_amdgcn_mfma_f32_16x16x32_bf16(a, b, qacc[fc], 0, 0, 0);
                }
            }
            __syncthreads();
        }
        #pragma unroll
        for (int fc = 0; fc < 2; fc++)
            #pragma unroll
            for (int r = 0; r < 4; r++)
                Qs[wr * 16 + g * 4 + r][wc * 32 + fc * 16 + l15] = f2bf(qacc[fc][r]);
        __syncthreads();
    }

    short8 qa0 = *(short8*)&Qs[qg * 16 + l15][g * 8];
    short8 qa1 = *(short8*)&Qs[qg * 16 + l15][32 + g * 8];

    // ---- K/V staging pointers (threads [0,256) stage kh=0, rest kh=1) ----
    int sh = t >> 8;
    int tt = t & 255;
    int row = tt >> 2, c0 = (tt & 3) * 16;
    const short* gK = Kb + (size_t)(sh * 512 + row) * DMODEL + h * DHEAD + c0;
    const short* gV = VbT + (size_t)(h * DHEAD + row) * M_TOK + sh * 512 + c0;

    short8 k0 = *(const short8*)gK;
    short8 k1 = *(const short8*)(gK + 8);
    short8 v0 = *(const short8*)gV;
    short8 v1 = *(const short8*)(gV + 8);

    f32x4 acc[4] = {};
    f32x4 rsum = {};

    for (int it = 0; it < 8; ++it) {
        *(short8*)&Ks[sh][row][c0]     = k0;
        *(short8*)&Ks[sh][row][c0 + 8] = k1;
        *(short8*)&Vt[sh][row][c0]     = v0;
        *(short8*)&Vt[sh][row][c0 + 8] = v1;
        __syncthreads();
        if (it < 7) {
            gK += (size_t)64 * DMODEL;
            gV += 64;
            k0 = *(const short8*)gK;
            k1 = *(const short8*)(gK + 8);
            v0 = *(const short8*)gV;
            v1 = *(const short8*)(gV + 8);
        }
        #pragma unroll
        for (int kt = 0; kt < 4; kt++) {
            short8 kf0 = *(short8*)&Ks[kh][kt * 16 + l15][g * 8];
            short8 kf1 = *(short8*)&Ks[kh][kt * 16 + l15][32 + g * 8];
            f32x4 e = {};
            e = __builtin_amdgcn_mfma_f32_16x16x32_bf16(qa0, kf0, e, 0, 0, 0);
            e = __builtin_amdgcn_mfma_f32_16x16x32_bf16(qa1, kf1, e, 0, 0, 0);
            #pragma unroll
            for (int r = 0; r < 4; r++) {
                float p = exp2f(e[r]);           // LOG2E folded into K
                rsum[r] += p;
                Ps[w][g * 4 + r][kt * 16 + l15] = f2bf(p);
            }
        }
        #pragma unroll
        for (int kb2 = 0; kb2 < 2; kb2++) {
            short8 pa = *(short8*)&Ps[w][l15][kb2 * 32 + g * 8];
            #pragma unroll
            for (int nt = 0; nt < 4; nt++) {
                short8 vf = *(short8*)&Vt[kh][nt * 16 + l15][kb2 * 32 + g * 8];
                acc[nt] = __builtin_amdgcn_mfma_f32_16x16x32_bf16(pa, vf, acc[nt], 0, 0, 0);
            }
        }
        __syncthreads();
    }

    // ---- two-pass merge (kh=1 partials -> kh=0) through dedicated region ----
    if (kh == 1) {
        pm.m.macc[qg][0][lane] = acc[0];
        pm.m.macc[qg][1][lane] = acc[1];
        pm.m.mrs[qg][lane] = rsum;
    }
    __syncthreads();
    if (kh == 0) {
        acc[0] += pm.m.macc[qg][0][lane];
        acc[1] += pm.m.macc[qg][1][lane];
        rsum += pm.m.mrs[qg][lane];
    }
    __syncthreads();
    if (kh == 1) {
        pm.m.macc[qg][0][lane] = acc[2];
        pm.m.macc[qg][1][lane] = acc[3];
    }
    __syncthreads();
    if (kh == 0) {
        acc[2] += pm.m.macc[qg][0][lane];
        acc[3] += pm.m.macc[qg][1][lane];
        #pragma unroll
        for (int r = 0; r < 4; r++) {
            float s = rsum[r];
            s += __shfl_xor(s, 1);
            s += __shfl_xor(s, 2);
            s += __shfl_xor(s, 4);
            s += __shfl_xor(s, 8);
            rsum[r] = s;
        }
        #pragma unroll
        for (int nt = 0; nt < 4; nt++)
            #pragma unroll
            for (int r = 0; r < 4; r++) {
                float y = acc[nt][r] / rsum[r];
                Yb[(size_t)(n0 + qg * 16 + g * 4 + r) * DMODEL + h * DHEAD + nt * 16 + l15] = f2bf(y);
            }
    }
}

// ---------------------------------------------------------------------------
extern "C" void kernel_launch(void* const* d_in, const int* in_sizes, int n_in,
                              void* d_out, int out_size, void* d_ws, size_t ws_size,
                              hipStream_t stream) {
    const float* xv = (const float*)d_in[0];
    const float* xt = (const float*)d_in[1];
    const float* wq = (const float*)d_in[2];
    const float* wk = (const float*)d_in[3];
    const float* wv = (const float*)d_in[4];
    const float* wo = (const float*)d_in[5];

    short* xvb = (short*)d_ws;              // 4096*512
    short* xtb = xvb + N_TOK * DMODEL;      // 1024*512
    short* wqb = xtb + M_TOK * DMODEL;      // 512*512 (B^T)
    short* wkb = wqb + DMODEL * DMODEL;
    short* wvb = wkb + DMODEL * DMODEL;
    short* wob = wvb + DMODEL * DMODEL;
    short* kbm = wob + DMODEL * DMODEL;     // 1024*512 (pre-scaled by LOG2E)
    short* vbt = kbm + M_TOK * DMODEL;      // 512*1024 (V^T)
    short* yb  = vbt + M_TOK * DMODEL;      // 4096*512

    pack_kernel<<<1280, 256, 0, stream>>>(xv, xt, wq, wk, wv, wo,
                                          xvb, xtb, wqb, wkb, wvb, wob);
    gemmKV<<<256, 512, 0, stream>>>(xtb, wkb, wvb, kbm, vbt);
    attn_kernel<<<512, 512, 0, stream>>>(xvb, wqb, kbm, vbt, yb);
    gemmOut<<<dim3(64, 8), 512, 0, stream>>>(yb, wob, (float*)d_out);
}